// Round 4
// baseline (394.723 us; speedup 1.0000x reference)
//
#include <hip/hip_runtime.h>
#include <cstdint>
#include <cstddef>
#include <math.h>

// RESK GCN forward: 4 graph-conv layers + residuals + log_softmax.
// R12: pipelined aggregation. R11 aggs ~49us each, HBM 25%, traffic floor
//      ~16us -> exposed gather latency (serial group chain). Now: wave-
//      uniform ng=ceil(deg/16) drives a scalar switch with a depth-2
//      static ping-pong pipeline (group g+1 bpermute+gather issued before
//      group g FMAs); row_start reads forced scalar via readfirstlane'd
//      wid; bpermute group offsets folded to ds offset immediates.
//      MFMA GEMM (R11), CSR build unchanged.

typedef unsigned int uint;
typedef unsigned short ushort;
typedef unsigned char uchar;

typedef __attribute__((ext_vector_type(8))) short bf16x8;
typedef __attribute__((ext_vector_type(4))) float f32x4;

constexpr int NB_ROWS = 256;   // rows per bucket
constexpr int CHUNK   = 2048;  // edges per bucket_kernel block
constexpr int CAP     = 4608;  // bucket window capacity (mean 4096, +8 sigma)

__device__ __forceinline__ uint f2bf(float f) {
    uint u = __float_as_uint(f);
    return (u + 0x7FFFu + ((u >> 16) & 1u)) >> 16;
}

__global__ void zero_ints(int* __restrict__ p, int n) {
    int i = blockIdx.x * blockDim.x + threadIdx.x;
    if (i < n) p[i] = 0;
}

// Build bf16 W^T copies: wt0 [64][128]; wt1,wt2 [64][64]; wt3 [64][64]
// (cols >=40 zero). wtX[c][k] = bf16(WX[k][c]).
__global__ void prep_wt(const float* __restrict__ W0, const float* __restrict__ W1,
                        const float* __restrict__ W2, const float* __restrict__ W3,
                        ushort* __restrict__ wt0, ushort* __restrict__ wt1,
                        ushort* __restrict__ wt2, ushort* __restrict__ wt3) {
    int i = blockIdx.x * 256 + threadIdx.x;
    if (i < 64 * 128) {
        int c = i >> 7, k = i & 127;
        wt0[i] = (ushort)f2bf(W0[k * 64 + c]);
    }
    if (i < 64 * 64) {
        int c = i >> 6, k = i & 63;
        wt1[i] = (ushort)f2bf(W1[k * 64 + c]);
        wt2[i] = (ushort)f2bf(W2[k * 64 + c]);
        wt3[i] = (c < 40) ? (ushort)f2bf(W3[k * 40 + c]) : (ushort)0;
    }
}

// Stage 1: bin edges by bucket (tgt>>8) in LDS; write per-(block,bucket) runs
// contiguously. Payload = src | w15<<17 (4B) + row byte (1B side array).
__global__ __launch_bounds__(512) void bucket_kernel(const int* __restrict__ src,
                                                     const int* __restrict__ tgt,
                                                     const float* __restrict__ w,
                                                     int* __restrict__ bcur,
                                                     uint* __restrict__ bkt,
                                                     uchar* __restrict__ brow,
                                                     int E, int NB) {
    __shared__ uint binned[CHUNK];
    __shared__ ushort binb[CHUNK];
    __shared__ uchar binr[CHUNK];
    __shared__ int hist[512];
    __shared__ int sc[512];
    __shared__ int cur[512];
    __shared__ int gbase[512];
    int tid = threadIdx.x;
    int e0 = blockIdx.x * CHUNK;
    int cnt = min(CHUNK, E - e0);
    hist[tid] = 0;
    __syncthreads();
    for (int i = tid; i < cnt; i += 512) atomicAdd(&hist[tgt[e0 + i] >> 8], 1);
    __syncthreads();
    int v = hist[tid];
    sc[tid] = v;
    __syncthreads();
    for (int off = 1; off < 512; off <<= 1) {
        int t = (tid >= off) ? sc[tid - off] : 0;
        __syncthreads();
        sc[tid] += t;
        __syncthreads();
    }
    int excl = sc[tid] - v;
    if (tid < NB && v > 0) gbase[tid] = atomicAdd(&bcur[tid], v);
    __syncthreads();
    hist[tid] = excl;
    cur[tid] = excl;
    __syncthreads();
    for (int i = tid; i < cnt; i += 512) {
        int t = tgt[e0 + i];
        int b = t >> 8;
        int r = atomicAdd(&cur[b], 1);
        float wf = w[e0 + i];
        uint w15 = (uint)(int)(wf * 32767.f + 0.5f);
        if (w15 > 32767u) w15 = 32767u;
        binned[r] = (uint)src[e0 + i] | (w15 << 17);
        binb[r] = (ushort)b;
        binr[r] = (uchar)(t & 255);
    }
    __syncthreads();
    for (int i = tid; i < cnt; i += 512) {
        int b = binb[i];
        int dst = gbase[b] + (i - hist[b]);
        if (dst < CAP) {
            bkt[(size_t)b * CAP + dst] = binned[i];
            brow[(size_t)b * CAP + dst] = binr[i];
        }
    }
}

// Stage 2: exclusive scan of bucket totals -> bucket bases; total -> row_start[N].
__global__ void bscan_kernel(const int* __restrict__ bcur, int* __restrict__ bbase,
                             int* __restrict__ row_start, int NB, int N) {
    __shared__ int sd[512];
    int tid = threadIdx.x;
    int tot = (tid < NB) ? min(bcur[tid], CAP) : 0;
    sd[tid] = tot;
    __syncthreads();
    for (int off = 1; off < 512; off <<= 1) {
        int t = (tid >= off) ? sd[tid - off] : 0;
        __syncthreads();
        sd[tid] += t;
        __syncthreads();
    }
    if (tid < NB) bbase[tid] = sd[tid] - tot;
    if (tid == 511) row_start[N] = sd[511];
}

// Stage 3: per-bucket row sort -> row_start + row-sorted 4B csr entries.
__global__ __launch_bounds__(1024) void rowsort_kernel(const uint* __restrict__ bkt,
                                                       const uchar* __restrict__ brow,
                                                       const int* __restrict__ bcur,
                                                       const int* __restrict__ bbase,
                                                       uint* __restrict__ csr,
                                                       int* __restrict__ row_start, int N) {
    __shared__ int hist[256];
    __shared__ int offs[256];
    int b = blockIdx.x;
    int tid = threadIdx.x;
    int cnt = min(bcur[b], CAP);
    const uint* win = bkt + (size_t)b * CAP;
    const uchar* wrow = brow + (size_t)b * CAP;
    if (tid < 256) hist[tid] = 0;
    __syncthreads();
    uint en[5];
    uchar er[5];
    int ne = 0;
#pragma unroll
    for (int k = 0; k < 5; ++k) {
        int i = tid + k * 1024;
        if (i < cnt) {
            en[k] = win[i];
            er[k] = wrow[i];
            atomicAdd(&hist[er[k]], 1);
            ne = k + 1;
        }
    }
    __syncthreads();
    int v = 0;
    if (tid < 256) { v = hist[tid]; offs[tid] = v; }
    __syncthreads();
    for (int off = 1; off < 256; off <<= 1) {
        int t = 0;
        if (tid < 256 && tid >= off) t = offs[tid - off];
        __syncthreads();
        if (tid < 256) offs[tid] += t;
        __syncthreads();
    }
    int gb = bbase[b];
    if (tid < 256) {
        int excl = offs[tid] - v;
        int row = (b << 8) + tid;
        if (row < N) row_start[row] = gb + excl;
        hist[tid] = excl;
    }
    __syncthreads();
#pragma unroll
    for (int k = 0; k < 5; ++k) {
        if (k < ne) {
            int pos = atomicAdd(&hist[er[k]], 1);
            csr[gb + pos] = en[k];
        }
    }
}

// support[n][c] = sum_k H[n][k] * W[k][c], output bf16 row stride 64.
// MFMA 16x16x32 bf16, operands swapped: A = Wt (C x K), B = H^T (K x nodes)
// => D[c][node]; lane&15 = node, 4*(lane>>4)+j = c => per lane one node x
// 4 consecutive cols -> packed dwordx2 store. Block = 64 nodes x 4 waves;
// wave wv owns nodes wv*16..wv*16+15, all 64 cols. H tile staged fp32->bf16
// in LDS, byte-col XOR ((row&7)<<4) swizzle, read as bf16x8 (ds_read_b128).
template <int K>
__global__ __launch_bounds__(256) void gemm_mfma(const float* __restrict__ H,
                                                 const ushort* __restrict__ Wt,
                                                 uint* __restrict__ out, int n) {
    constexpr int NT = K / 32;  // K-steps
    __shared__ ushort alds[64 * K];
    int tid = threadIdx.x;
    int nbase = blockIdx.x * 64;
    int rows = min(64, n - nbase);

    // Stage H tile (64 x K fp32) -> bf16 LDS, coalesced float4 reads.
    const float4* Hg = (const float4*)(H + (size_t)nbase * K);
#pragma unroll
    for (int it = 0; it < K / 16; ++it) {
        int i = tid + it * 256;     // float4 index within tile
        int r = i / (K / 4);
        int c4 = i % (K / 4);
        if (r < rows) {
            float4 v = Hg[i];
            uint2 pk;
            pk.x = f2bf(v.x) | (f2bf(v.y) << 16);
            pk.y = f2bf(v.z) | (f2bf(v.w) << 16);
            uint bcol = ((uint)(c4 * 8)) ^ (((uint)(r & 7)) << 4);
            *(uint2*)((char*)alds + r * (K * 2) + bcol) = pk;
        }
    }

    int wv = __builtin_amdgcn_readfirstlane(tid >> 6);
    int l = tid & 63;
    int lr = l & 15;
    int lh = l >> 4;

    // A-operand fragments: Wt[c = ct*16+lr][k = ks*32 + lh*8 .. +8].
    bf16x8 wf[4][NT];
#pragma unroll
    for (int ct = 0; ct < 4; ++ct)
#pragma unroll
        for (int ks = 0; ks < NT; ++ks)
            wf[ct][ks] = *(const bf16x8*)(const void*)(Wt + (ct * 16 + lr) * K + ks * 32 + lh * 8);

    __syncthreads();

    f32x4 acc[4];
#pragma unroll
    for (int ct = 0; ct < 4; ++ct) acc[ct] = (f32x4){0.f, 0.f, 0.f, 0.f};

    int row = wv * 16 + lr;  // node within tile
#pragma unroll
    for (int ks = 0; ks < NT; ++ks) {
        uint bcol = ((uint)(ks * 64 + lh * 16)) ^ (((uint)(row & 7)) << 4);
        bf16x8 hf = *(const bf16x8*)((const char*)alds + row * (K * 2) + bcol);
#pragma unroll
        for (int ct = 0; ct < 4; ++ct)
            acc[ct] = __builtin_amdgcn_mfma_f32_16x16x32_bf16(wf[ct][ks], hf, acc[ct], 0, 0, 0);
    }

    int node = nbase + row;
    if (node < n) {
        uint* orow = out + (size_t)node * 32;  // 64 bf16 = 32 uints per row
#pragma unroll
        for (int ct = 0; ct < 4; ++ct) {
            uint2 pk;
            pk.x = f2bf(acc[ct][0]) | (f2bf(acc[ct][1]) << 16);
            pk.y = f2bf(acc[ct][2]) | (f2bf(acc[ct][3]) << 16);
            *(uint2*)(orow + ct * 8 + lh * 2) = pk;  // cols ct*16+lh*4 .. +3
        }
    }
}

__device__ __forceinline__ float wval(uint d) {
    return (float)(d >> 17) * (1.0f / 32767.f);
}

__device__ __forceinline__ float blo(uint u) { return __uint_as_float(u << 16); }
__device__ __forceinline__ float bhi(uint u) { return __uint_as_float(u & 0xFFFF0000u); }

// One 16-edge group: 4 edges per lane (slots q, q+4, q+8, q+12 pattern via
// k*4+q), dwordx2 gather of cols 4c..4c+3. Group index g is compile-time
// in the unrolled switch -> bpermute offset folds to the DS offset field.
struct Grp {
    uint dd[4];
    uint2 uu[4];
};

__device__ __forceinline__ void gload(int g, int q4, uint mye, const char* sb,
                                      uint voff, Grp& G) {
#pragma unroll
    for (int k = 0; k < 4; ++k)
        G.dd[k] = (uint)__builtin_amdgcn_ds_bpermute(q4 + ((g * 16 + 4 * k) << 2), (int)mye);
#pragma unroll
    for (int k = 0; k < 4; ++k)
        G.uu[k] = *(const uint2*)(sb + (((G.dd[k] & 0x1FFFFu) << 7) | voff));
}

__device__ __forceinline__ void gacc(const Grp& G, float& a0, float& a1,
                                     float& a2, float& a3) {
#pragma unroll
    for (int k = 0; k < 4; ++k) {
        float wv = wval(G.dd[k]);
        a0 = fmaf(blo(G.uu[k].x), wv, a0);
        a1 = fmaf(bhi(G.uu[k].x), wv, a1);
        a2 = fmaf(blo(G.uu[k].y), wv, a2);
        a3 = fmaf(bhi(G.uu[k].y), wv, a3);
    }
}

// Shared agg body: accumulates weighted gather of sb rows for node wid's
// CSR range into a0..a3 (cols 4c..4c+3 of lane c=lane&15, partial across
// 4 quad-slots; combine with shfl_xor 16,32 after).
__device__ __forceinline__ void agg_body(const ushort* __restrict__ sb,
                                         const int* __restrict__ row_start,
                                         const uint* __restrict__ csr, int wid,
                                         int lane, float& a0, float& a1,
                                         float& a2, float& a3) {
    int q4 = (lane >> 4) << 2;
    int beg = row_start[wid];      // wid is SGPR -> s_load
    int end = row_start[wid + 1];
    uint voff = (uint)((lane & 15) << 3);
    const char* sbc = (const char*)sb;
    for (int e0 = beg; e0 < end; e0 += 64) {
        int ei = e0 + lane;
        uint mye = (ei < end) ? csr[ei] : 0u;
        int m = end - e0;
        if (m > 64) m = 64;
        int ng = (m + 15) >> 4;  // 1..4, wave-uniform -> scalar branch
        Grp A, B;
        gload(0, q4, mye, sbc, voff, A);
        switch (ng) {
            case 1:
                gacc(A, a0, a1, a2, a3);
                break;
            case 2:
                gload(1, q4, mye, sbc, voff, B);
                gacc(A, a0, a1, a2, a3);
                gacc(B, a0, a1, a2, a3);
                break;
            case 3:
                gload(1, q4, mye, sbc, voff, B);
                gacc(A, a0, a1, a2, a3);
                gload(2, q4, mye, sbc, voff, A);
                gacc(B, a0, a1, a2, a3);
                gacc(A, a0, a1, a2, a3);
                break;
            default:
                gload(1, q4, mye, sbc, voff, B);
                gacc(A, a0, a1, a2, a3);
                gload(2, q4, mye, sbc, voff, A);
                gacc(B, a0, a1, a2, a3);
                gload(3, q4, mye, sbc, voff, B);
                gacc(A, a0, a1, a2, a3);
                gacc(B, a0, a1, a2, a3);
                break;
        }
    }
}

// Quad-edge wave-per-node aggregation, C=64, depth-2 pipelined groups.
// out may alias resid.
__global__ __launch_bounds__(256) void agg64_kernel(const ushort* __restrict__ sb,
                                                    const int* __restrict__ row_start,
                                                    const uint* __restrict__ csr,
                                                    const float* __restrict__ bias,
                                                    const float* __restrict__ resid,
                                                    float* __restrict__ out, int n) {
    int wid = (blockIdx.x * blockDim.x + threadIdx.x) >> 6;
    int lane = threadIdx.x & 63;
    if (wid >= n) return;
    wid = __builtin_amdgcn_readfirstlane(wid);
    float a0 = 0.f, a1 = 0.f, a2 = 0.f, a3 = 0.f;
    agg_body(sb, row_start, csr, wid, lane, a0, a1, a2, a3);
    a0 += __shfl_xor(a0, 16); a1 += __shfl_xor(a1, 16);
    a2 += __shfl_xor(a2, 16); a3 += __shfl_xor(a3, 16);
    a0 += __shfl_xor(a0, 32); a1 += __shfl_xor(a1, 32);
    a2 += __shfl_xor(a2, 32); a3 += __shfl_xor(a3, 32);
    int c = lane & 15;
    if (lane < 16) {
        float4 bv = *(const float4*)(bias + 4 * c);
        float h0 = fmaxf(a0 + bv.x, 0.f);
        float h1 = fmaxf(a1 + bv.y, 0.f);
        float h2 = fmaxf(a2 + bv.z, 0.f);
        float h3 = fmaxf(a3 + bv.w, 0.f);
        if (resid) {
            float4 rv = *(const float4*)(resid + (size_t)wid * 64 + 4 * c);
            h0 += rv.x;
            h1 += rv.y;
            h2 += rv.z;
            h3 += rv.w;
        }
        *(float4*)(out + (size_t)wid * 64 + 4 * c) = make_float4(h0, h1, h2, h3);
    }
}

// Final layer: pipelined agg over stride-64 support (cols 0..39 live) +
// bias + fused log_softmax (reductions across the 16 col-group lanes).
__global__ __launch_bounds__(256) void agg_final_kernel(const ushort* __restrict__ sb,
                                                        const int* __restrict__ row_start,
                                                        const uint* __restrict__ csr,
                                                        const float* __restrict__ bias,
                                                        float* __restrict__ out, int n) {
    int wid = (blockIdx.x * blockDim.x + threadIdx.x) >> 6;
    int lane = threadIdx.x & 63;
    if (wid >= n) return;
    wid = __builtin_amdgcn_readfirstlane(wid);
    float a0 = 0.f, a1 = 0.f, a2 = 0.f, a3 = 0.f;
    agg_body(sb, row_start, csr, wid, lane, a0, a1, a2, a3);
    a0 += __shfl_xor(a0, 16); a1 += __shfl_xor(a1, 16);
    a2 += __shfl_xor(a2, 16); a3 += __shfl_xor(a3, 16);
    a0 += __shfl_xor(a0, 32); a1 += __shfl_xor(a1, 32);
    a2 += __shfl_xor(a2, 32); a3 += __shfl_xor(a3, 32);
    int c = lane & 15;
    bool act = c < 10;  // cols 4c..4c+3 < 40
    float v0 = -INFINITY, v1 = -INFINITY, v2 = -INFINITY, v3 = -INFINITY;
    if (act) {
        float4 bv = *(const float4*)(bias + 4 * c);
        v0 = a0 + bv.x;
        v1 = a1 + bv.y;
        v2 = a2 + bv.z;
        v3 = a3 + bv.w;
    }
    float m = fmaxf(fmaxf(v0, v1), fmaxf(v2, v3));
#pragma unroll
    for (int d = 1; d < 16; d <<= 1) m = fmaxf(m, __shfl_xor(m, d));
    float ex = act ? (expf(v0 - m) + expf(v1 - m) + expf(v2 - m) + expf(v3 - m)) : 0.f;
#pragma unroll
    for (int d = 1; d < 16; d <<= 1) ex += __shfl_xor(ex, d);
    float lse = m + logf(ex);
    if (act && lane < 16)
        *(float4*)(out + (size_t)wid * 40 + 4 * c) =
            make_float4(v0 - lse, v1 - lse, v2 - lse, v3 - lse);
}

extern "C" void kernel_launch(void* const* d_in, const int* in_sizes, int n_in,
                              void* d_out, int out_size, void* d_ws, size_t ws_size,
                              hipStream_t stream) {
    const float* x   = (const float*)d_in[0];
    const int*   src = (const int*)d_in[1];
    const int*   tgt = (const int*)d_in[2];
    const float* mw  = (const float*)d_in[3];
    const float* W0  = (const float*)d_in[4];
    const float* b0  = (const float*)d_in[5];
    const float* W1  = (const float*)d_in[6];
    const float* b1  = (const float*)d_in[7];
    const float* W2  = (const float*)d_in[8];
    const float* b2  = (const float*)d_in[9];
    const float* W3  = (const float*)d_in[10];
    const float* b3  = (const float*)d_in[11];
    float* out = (float*)d_out;

    const int N = in_sizes[0] / 128;
    const int E = in_sizes[1];
    const int NB = (N + NB_ROWS - 1) / NB_ROWS;  // 391 buckets (<=512)

    // Workspace carve-out (~57 MB)
    char* p = (char*)d_ws;
    auto carve = [&](size_t bytes) {
        char* r = p;
        p += (bytes + 255) & ~size_t(255);
        return r;
    };
    int*    bcur      = (int*)carve((size_t)NB * 4);
    int*    bbase     = (int*)carve((size_t)NB * 4);
    int*    row_start = (int*)carve((size_t)(N + 1) * 4);
    uint*   bkt       = (uint*)carve((size_t)NB * CAP * 4);   // 7.2 MB
    uchar*  brow      = (uchar*)carve((size_t)NB * CAP);      // 1.8 MB
    uint*   csr       = (uint*)carve((size_t)E * 4);          // 6.4 MB
    ushort* support   = (ushort*)carve((size_t)N * 64 * 2);   // 12.8 MB (stride 64)
    float*  h         = (float*)carve((size_t)N * 64 * 4);    // 25.6 MB
    ushort* wt0       = (ushort*)carve((size_t)64 * 128 * 2); // 16 KB
    ushort* wt1       = (ushort*)carve((size_t)64 * 64 * 2);  // 8 KB
    ushort* wt2       = (ushort*)carve((size_t)64 * 64 * 2);  // 8 KB
    ushort* wt3       = (ushort*)carve((size_t)64 * 64 * 2);  // 8 KB

    int gblocks = (N + 63) / 64;     // 64 nodes per block, 4 waves
    int ablocks = (N + 3) / 4;       // 4 waves/block, wave per node

    // ---- CSR build + weight prep ----
    zero_ints<<<(NB + 255) / 256, 256, 0, stream>>>(bcur, NB);
    prep_wt<<<32, 256, 0, stream>>>(W0, W1, W2, W3, wt0, wt1, wt2, wt3);
    bucket_kernel<<<(E + CHUNK - 1) / CHUNK, 512, 0, stream>>>(src, tgt, mw, bcur, bkt, brow, E, NB);
    bscan_kernel<<<1, 512, 0, stream>>>(bcur, bbase, row_start, NB, N);
    rowsort_kernel<<<NB, 1024, 0, stream>>>(bkt, brow, bcur, bbase, csr, row_start, N);

    // ---- Layer 0: h = relu(A @ (x @ W0) + b0) ----
    gemm_mfma<128><<<gblocks, 256, 0, stream>>>(x, wt0, (uint*)support, N);
    agg64_kernel<<<ablocks, 256, 0, stream>>>(support, row_start, csr, b0, nullptr, h, N);
    // ---- Layer 1: h = relu(A @ (h @ W1) + b1) + h ----
    gemm_mfma<64><<<gblocks, 256, 0, stream>>>(h, wt1, (uint*)support, N);
    agg64_kernel<<<ablocks, 256, 0, stream>>>(support, row_start, csr, b1, h, h, N);
    // ---- Layer 2 ----
    gemm_mfma<64><<<gblocks, 256, 0, stream>>>(h, wt2, (uint*)support, N);
    agg64_kernel<<<ablocks, 256, 0, stream>>>(support, row_start, csr, b2, h, h, N);
    // ---- Layer 3: out = log_softmax(A @ (h @ W3) + b3); W3 zero-padded ----
    gemm_mfma<64><<<gblocks, 256, 0, stream>>>(h, wt3, (uint*)support, N);
    agg_final_kernel<<<ablocks, 256, 0, stream>>>(support, row_start, csr, b3, out, N);
}

// Round 5
// 356.179 us; speedup vs baseline: 1.1082x; 1.1082x over previous
//
#include <hip/hip_runtime.h>
#include <cstdint>
#include <cstddef>
#include <math.h>

// RESK GCN forward: 4 graph-conv layers + residuals + log_softmax.
// R13: 4-nodes-per-wave aggregation. R8/R9/R12 aggs all ~50us with FETCH
//      pinned at 80MB -> not VALU-bound, not byte-bound; bound by per-node
//      serial chain x node concurrency (1 node/wave, 57% of rows ng=1 so
//      R12's in-node pipeline never engaged). Now lane group g=lane>>4 owns
//      node n0+g (c=lane&15 owns cols 4c..4c+3); csr is row-sorted so the
//      4 nodes share one coop 64-entry window; 4 independent gather streams
//      + 4-deep rounds = up to 16 gathers in flight; cross-slot combine
//      deleted; softmax for 4 nodes in parallel. MFMA GEMM (R11) and CSR
//      build unchanged.

typedef unsigned int uint;
typedef unsigned short ushort;
typedef unsigned char uchar;

typedef __attribute__((ext_vector_type(8))) short bf16x8;
typedef __attribute__((ext_vector_type(4))) float f32x4;

constexpr int NB_ROWS = 256;   // rows per bucket
constexpr int CHUNK   = 2048;  // edges per bucket_kernel block
constexpr int CAP     = 4608;  // bucket window capacity (mean 4096, +8 sigma)

__device__ __forceinline__ uint f2bf(float f) {
    uint u = __float_as_uint(f);
    return (u + 0x7FFFu + ((u >> 16) & 1u)) >> 16;
}

__global__ void zero_ints(int* __restrict__ p, int n) {
    int i = blockIdx.x * blockDim.x + threadIdx.x;
    if (i < n) p[i] = 0;
}

// Build bf16 W^T copies: wt0 [64][128]; wt1,wt2 [64][64]; wt3 [64][64]
// (cols >=40 zero). wtX[c][k] = bf16(WX[k][c]).
__global__ void prep_wt(const float* __restrict__ W0, const float* __restrict__ W1,
                        const float* __restrict__ W2, const float* __restrict__ W3,
                        ushort* __restrict__ wt0, ushort* __restrict__ wt1,
                        ushort* __restrict__ wt2, ushort* __restrict__ wt3) {
    int i = blockIdx.x * 256 + threadIdx.x;
    if (i < 64 * 128) {
        int c = i >> 7, k = i & 127;
        wt0[i] = (ushort)f2bf(W0[k * 64 + c]);
    }
    if (i < 64 * 64) {
        int c = i >> 6, k = i & 63;
        wt1[i] = (ushort)f2bf(W1[k * 64 + c]);
        wt2[i] = (ushort)f2bf(W2[k * 64 + c]);
        wt3[i] = (c < 40) ? (ushort)f2bf(W3[k * 40 + c]) : (ushort)0;
    }
}

// Stage 1: bin edges by bucket (tgt>>8) in LDS; write per-(block,bucket) runs
// contiguously. Payload = src | w15<<17 (4B) + row byte (1B side array).
__global__ __launch_bounds__(512) void bucket_kernel(const int* __restrict__ src,
                                                     const int* __restrict__ tgt,
                                                     const float* __restrict__ w,
                                                     int* __restrict__ bcur,
                                                     uint* __restrict__ bkt,
                                                     uchar* __restrict__ brow,
                                                     int E, int NB) {
    __shared__ uint binned[CHUNK];
    __shared__ ushort binb[CHUNK];
    __shared__ uchar binr[CHUNK];
    __shared__ int hist[512];
    __shared__ int sc[512];
    __shared__ int cur[512];
    __shared__ int gbase[512];
    int tid = threadIdx.x;
    int e0 = blockIdx.x * CHUNK;
    int cnt = min(CHUNK, E - e0);
    hist[tid] = 0;
    __syncthreads();
    for (int i = tid; i < cnt; i += 512) atomicAdd(&hist[tgt[e0 + i] >> 8], 1);
    __syncthreads();
    int v = hist[tid];
    sc[tid] = v;
    __syncthreads();
    for (int off = 1; off < 512; off <<= 1) {
        int t = (tid >= off) ? sc[tid - off] : 0;
        __syncthreads();
        sc[tid] += t;
        __syncthreads();
    }
    int excl = sc[tid] - v;
    if (tid < NB && v > 0) gbase[tid] = atomicAdd(&bcur[tid], v);
    __syncthreads();
    hist[tid] = excl;
    cur[tid] = excl;
    __syncthreads();
    for (int i = tid; i < cnt; i += 512) {
        int t = tgt[e0 + i];
        int b = t >> 8;
        int r = atomicAdd(&cur[b], 1);
        float wf = w[e0 + i];
        uint w15 = (uint)(int)(wf * 32767.f + 0.5f);
        if (w15 > 32767u) w15 = 32767u;
        binned[r] = (uint)src[e0 + i] | (w15 << 17);
        binb[r] = (ushort)b;
        binr[r] = (uchar)(t & 255);
    }
    __syncthreads();
    for (int i = tid; i < cnt; i += 512) {
        int b = binb[i];
        int dst = gbase[b] + (i - hist[b]);
        if (dst < CAP) {
            bkt[(size_t)b * CAP + dst] = binned[i];
            brow[(size_t)b * CAP + dst] = binr[i];
        }
    }
}

// Stage 2: exclusive scan of bucket totals -> bucket bases; total -> row_start[N].
__global__ void bscan_kernel(const int* __restrict__ bcur, int* __restrict__ bbase,
                             int* __restrict__ row_start, int NB, int N) {
    __shared__ int sd[512];
    int tid = threadIdx.x;
    int tot = (tid < NB) ? min(bcur[tid], CAP) : 0;
    sd[tid] = tot;
    __syncthreads();
    for (int off = 1; off < 512; off <<= 1) {
        int t = (tid >= off) ? sd[tid - off] : 0;
        __syncthreads();
        sd[tid] += t;
        __syncthreads();
    }
    if (tid < NB) bbase[tid] = sd[tid] - tot;
    if (tid == 511) row_start[N] = sd[511];
}

// Stage 3: per-bucket row sort -> row_start + row-sorted 4B csr entries.
__global__ __launch_bounds__(1024) void rowsort_kernel(const uint* __restrict__ bkt,
                                                       const uchar* __restrict__ brow,
                                                       const int* __restrict__ bcur,
                                                       const int* __restrict__ bbase,
                                                       uint* __restrict__ csr,
                                                       int* __restrict__ row_start, int N) {
    __shared__ int hist[256];
    __shared__ int offs[256];
    int b = blockIdx.x;
    int tid = threadIdx.x;
    int cnt = min(bcur[b], CAP);
    const uint* win = bkt + (size_t)b * CAP;
    const uchar* wrow = brow + (size_t)b * CAP;
    if (tid < 256) hist[tid] = 0;
    __syncthreads();
    uint en[5];
    uchar er[5];
    int ne = 0;
#pragma unroll
    for (int k = 0; k < 5; ++k) {
        int i = tid + k * 1024;
        if (i < cnt) {
            en[k] = win[i];
            er[k] = wrow[i];
            atomicAdd(&hist[er[k]], 1);
            ne = k + 1;
        }
    }
    __syncthreads();
    int v = 0;
    if (tid < 256) { v = hist[tid]; offs[tid] = v; }
    __syncthreads();
    for (int off = 1; off < 256; off <<= 1) {
        int t = 0;
        if (tid < 256 && tid >= off) t = offs[tid - off];
        __syncthreads();
        if (tid < 256) offs[tid] += t;
        __syncthreads();
    }
    int gb = bbase[b];
    if (tid < 256) {
        int excl = offs[tid] - v;
        int row = (b << 8) + tid;
        if (row < N) row_start[row] = gb + excl;
        hist[tid] = excl;
    }
    __syncthreads();
#pragma unroll
    for (int k = 0; k < 5; ++k) {
        if (k < ne) {
            int pos = atomicAdd(&hist[er[k]], 1);
            csr[gb + pos] = en[k];
        }
    }
}

// support[n][c] = sum_k H[n][k] * W[k][c], output bf16 row stride 64.
// MFMA 16x16x32 bf16, operands swapped: A = Wt (C x K), B = H^T (K x nodes)
// => D[c][node]; lane&15 = node, 4*(lane>>4)+j = c => per lane one node x
// 4 consecutive cols -> packed dwordx2 store. Block = 64 nodes x 4 waves;
// wave wv owns nodes wv*16..wv*16+15, all 64 cols. H tile staged fp32->bf16
// in LDS, byte-col XOR ((row&7)<<4) swizzle, read as bf16x8 (ds_read_b128).
template <int K>
__global__ __launch_bounds__(256) void gemm_mfma(const float* __restrict__ H,
                                                 const ushort* __restrict__ Wt,
                                                 uint* __restrict__ out, int n) {
    constexpr int NT = K / 32;  // K-steps
    __shared__ ushort alds[64 * K];
    int tid = threadIdx.x;
    int nbase = blockIdx.x * 64;
    int rows = min(64, n - nbase);

    // Stage H tile (64 x K fp32) -> bf16 LDS, coalesced float4 reads.
    const float4* Hg = (const float4*)(H + (size_t)nbase * K);
#pragma unroll
    for (int it = 0; it < K / 16; ++it) {
        int i = tid + it * 256;     // float4 index within tile
        int r = i / (K / 4);
        int c4 = i % (K / 4);
        if (r < rows) {
            float4 v = Hg[i];
            uint2 pk;
            pk.x = f2bf(v.x) | (f2bf(v.y) << 16);
            pk.y = f2bf(v.z) | (f2bf(v.w) << 16);
            uint bcol = ((uint)(c4 * 8)) ^ (((uint)(r & 7)) << 4);
            *(uint2*)((char*)alds + r * (K * 2) + bcol) = pk;
        }
    }

    int wv = __builtin_amdgcn_readfirstlane(tid >> 6);
    int l = tid & 63;
    int lr = l & 15;
    int lh = l >> 4;

    // A-operand fragments: Wt[c = ct*16+lr][k = ks*32 + lh*8 .. +8].
    bf16x8 wf[4][NT];
#pragma unroll
    for (int ct = 0; ct < 4; ++ct)
#pragma unroll
        for (int ks = 0; ks < NT; ++ks)
            wf[ct][ks] = *(const bf16x8*)(const void*)(Wt + (ct * 16 + lr) * K + ks * 32 + lh * 8);

    __syncthreads();

    f32x4 acc[4];
#pragma unroll
    for (int ct = 0; ct < 4; ++ct) acc[ct] = (f32x4){0.f, 0.f, 0.f, 0.f};

    int row = wv * 16 + lr;  // node within tile
#pragma unroll
    for (int ks = 0; ks < NT; ++ks) {
        uint bcol = ((uint)(ks * 64 + lh * 16)) ^ (((uint)(row & 7)) << 4);
        bf16x8 hf = *(const bf16x8*)((const char*)alds + row * (K * 2) + bcol);
#pragma unroll
        for (int ct = 0; ct < 4; ++ct)
            acc[ct] = __builtin_amdgcn_mfma_f32_16x16x32_bf16(wf[ct][ks], hf, acc[ct], 0, 0, 0);
    }

    int node = nbase + row;
    if (node < n) {
        uint* orow = out + (size_t)node * 32;  // 64 bf16 = 32 uints per row
#pragma unroll
        for (int ct = 0; ct < 4; ++ct) {
            uint2 pk;
            pk.x = f2bf(acc[ct][0]) | (f2bf(acc[ct][1]) << 16);
            pk.y = f2bf(acc[ct][2]) | (f2bf(acc[ct][3]) << 16);
            *(uint2*)(orow + ct * 8 + lh * 2) = pk;  // cols ct*16+lh*4 .. +3
        }
    }
}

__device__ __forceinline__ float wval(uint d) {
    return (float)(d >> 17) * (1.0f / 32767.f);
}

__device__ __forceinline__ float blo(uint u) { return __uint_as_float(u << 16); }
__device__ __forceinline__ float bhi(uint u) { return __uint_as_float(u & 0xFFFF0000u); }

// 4-nodes-per-wave agg body. Lane group g=lane>>4 owns node n0+g; c=lane&15
// owns cols 4c..4c+3 (dwordx2 gather, 16 lanes cover the 128B row). The 4
// nodes' csr ranges are contiguous (row-sorted csr): coop-load 64-entry
// windows; group g consumes its slice [lo,hi) of each window in rounds of 4
// edges (bpermute broadcast; dead lanes masked to entry 0 -> w=0, gathers
// L1-hot row 0). Accumulators are full per-node sums (no cross-slot combine).
__device__ __forceinline__ void agg4_body(const ushort* __restrict__ sb,
                                          const int* __restrict__ row_start,
                                          const uint* __restrict__ csr, int n0,
                                          int lane, int N, float& a0, float& a1,
                                          float& a2, float& a3) {
    int g = lane >> 4;
    uint voff = (uint)((lane & 15) << 3);
    const char* sbc = (const char*)sb;

    int idx = n0 + lane;
    if (idx > N) idx = N;
    int rsv = (lane <= 4) ? row_start[idx] : 0;
    int rs0 = __shfl(rsv, 0);
    int myb = __shfl(rsv, g);       // this node's range begin
    int mye = __shfl(rsv, g + 1);   // this node's range end
    int tend = __shfl(rsv, 4);      // end of wave's 4-node span

    for (int W0 = rs0; W0 < tend; W0 += 64) {
        int ei = W0 + lane;
        uint entry = (ei < tend) ? csr[ei] : 0u;
        int lo = myb - W0;
        if (lo < 0) lo = 0;
        int hi = mye - W0;
        if (hi > 64) hi = 64;
        int cnt = hi - lo;
        if (cnt < 0) cnt = 0;
        // wave-uniform max rounds (keep all lanes active through bpermute)
        int mx = cnt;
        mx = max(mx, __shfl_xor(mx, 16));
        mx = max(mx, __shfl_xor(mx, 32));
        for (int o = 0; o < mx; o += 4) {
            uint dd[4];
            uint2 uu[4];
#pragma unroll
            for (int j = 0; j < 4; ++j) {
                int p = (lo + o + j) & 63;
                uint d = (uint)__builtin_amdgcn_ds_bpermute(p << 2, (int)entry);
                dd[j] = ((o + j) < cnt) ? d : 0u;
            }
#pragma unroll
            for (int j = 0; j < 4; ++j)
                uu[j] = *(const uint2*)(sbc + (((dd[j] & 0x1FFFFu) << 7) | voff));
#pragma unroll
            for (int j = 0; j < 4; ++j) {
                float wv = wval(dd[j]);
                a0 = fmaf(blo(uu[j].x), wv, a0);
                a1 = fmaf(bhi(uu[j].x), wv, a1);
                a2 = fmaf(blo(uu[j].y), wv, a2);
                a3 = fmaf(bhi(uu[j].y), wv, a3);
            }
        }
    }
}

// Middle layers: relu(agg + bias) (+ resid). All 64 lanes write: group g
// stores node n0+g cols 4c..4c+3. out may alias resid.
__global__ __launch_bounds__(256) void agg64_kernel(const ushort* __restrict__ sb,
                                                    const int* __restrict__ row_start,
                                                    const uint* __restrict__ csr,
                                                    const float* __restrict__ bias,
                                                    const float* __restrict__ resid,
                                                    float* __restrict__ out, int n) {
    int wid = (blockIdx.x * blockDim.x + threadIdx.x) >> 6;   // wave id
    int lane = threadIdx.x & 63;
    int n0 = wid * 4;
    if (n0 >= n) return;
    float a0 = 0.f, a1 = 0.f, a2 = 0.f, a3 = 0.f;
    agg4_body(sb, row_start, csr, n0, lane, n, a0, a1, a2, a3);
    int g = lane >> 4;
    int c = lane & 15;
    int nd = n0 + g;
    if (nd < n) {
        float4 bv = *(const float4*)(bias + 4 * c);
        float h0 = fmaxf(a0 + bv.x, 0.f);
        float h1 = fmaxf(a1 + bv.y, 0.f);
        float h2 = fmaxf(a2 + bv.z, 0.f);
        float h3 = fmaxf(a3 + bv.w, 0.f);
        if (resid) {
            float4 rv = *(const float4*)(resid + (size_t)nd * 64 + 4 * c);
            h0 += rv.x;
            h1 += rv.y;
            h2 += rv.z;
            h3 += rv.w;
        }
        *(float4*)(out + (size_t)nd * 64 + 4 * c) = make_float4(h0, h1, h2, h3);
    }
}

// Final layer: agg over stride-64 support (cols 0..39 live) + bias + fused
// log_softmax; reductions run within each 16-lane group (xor 1,2,4,8), so
// the wave's 4 nodes compute softmax in parallel.
__global__ __launch_bounds__(256) void agg_final_kernel(const ushort* __restrict__ sb,
                                                        const int* __restrict__ row_start,
                                                        const uint* __restrict__ csr,
                                                        const float* __restrict__ bias,
                                                        float* __restrict__ out, int n) {
    int wid = (blockIdx.x * blockDim.x + threadIdx.x) >> 6;
    int lane = threadIdx.x & 63;
    int n0 = wid * 4;
    if (n0 >= n) return;
    float a0 = 0.f, a1 = 0.f, a2 = 0.f, a3 = 0.f;
    agg4_body(sb, row_start, csr, n0, lane, n, a0, a1, a2, a3);
    int g = lane >> 4;
    int c = lane & 15;
    int nd = n0 + g;
    bool act = c < 10;  // cols 4c..4c+3 < 40
    float v0 = -INFINITY, v1 = -INFINITY, v2 = -INFINITY, v3 = -INFINITY;
    if (act) {
        float4 bv = *(const float4*)(bias + 4 * c);
        v0 = a0 + bv.x;
        v1 = a1 + bv.y;
        v2 = a2 + bv.z;
        v3 = a3 + bv.w;
    }
    float m = fmaxf(fmaxf(v0, v1), fmaxf(v2, v3));
#pragma unroll
    for (int d = 1; d < 16; d <<= 1) m = fmaxf(m, __shfl_xor(m, d));
    float ex = act ? (expf(v0 - m) + expf(v1 - m) + expf(v2 - m) + expf(v3 - m)) : 0.f;
#pragma unroll
    for (int d = 1; d < 16; d <<= 1) ex += __shfl_xor(ex, d);
    float lse = m + logf(ex);
    if (act && nd < n)
        *(float4*)(out + (size_t)nd * 40 + 4 * c) =
            make_float4(v0 - lse, v1 - lse, v2 - lse, v3 - lse);
}

extern "C" void kernel_launch(void* const* d_in, const int* in_sizes, int n_in,
                              void* d_out, int out_size, void* d_ws, size_t ws_size,
                              hipStream_t stream) {
    const float* x   = (const float*)d_in[0];
    const int*   src = (const int*)d_in[1];
    const int*   tgt = (const int*)d_in[2];
    const float* mw  = (const float*)d_in[3];
    const float* W0  = (const float*)d_in[4];
    const float* b0  = (const float*)d_in[5];
    const float* W1  = (const float*)d_in[6];
    const float* b1  = (const float*)d_in[7];
    const float* W2  = (const float*)d_in[8];
    const float* b2  = (const float*)d_in[9];
    const float* W3  = (const float*)d_in[10];
    const float* b3  = (const float*)d_in[11];
    float* out = (float*)d_out;

    const int N = in_sizes[0] / 128;
    const int E = in_sizes[1];
    const int NB = (N + NB_ROWS - 1) / NB_ROWS;  // 391 buckets (<=512)

    // Workspace carve-out (~57 MB)
    char* p = (char*)d_ws;
    auto carve = [&](size_t bytes) {
        char* r = p;
        p += (bytes + 255) & ~size_t(255);
        return r;
    };
    int*    bcur      = (int*)carve((size_t)NB * 4);
    int*    bbase     = (int*)carve((size_t)NB * 4);
    int*    row_start = (int*)carve((size_t)(N + 1) * 4);
    uint*   bkt       = (uint*)carve((size_t)NB * CAP * 4);   // 7.2 MB
    uchar*  brow      = (uchar*)carve((size_t)NB * CAP);      // 1.8 MB
    uint*   csr       = (uint*)carve((size_t)E * 4);          // 6.4 MB
    ushort* support   = (ushort*)carve((size_t)N * 64 * 2);   // 12.8 MB (stride 64)
    float*  h         = (float*)carve((size_t)N * 64 * 4);    // 25.6 MB
    ushort* wt0       = (ushort*)carve((size_t)64 * 128 * 2); // 16 KB
    ushort* wt1       = (ushort*)carve((size_t)64 * 64 * 2);  // 8 KB
    ushort* wt2       = (ushort*)carve((size_t)64 * 64 * 2);  // 8 KB
    ushort* wt3       = (ushort*)carve((size_t)64 * 64 * 2);  // 8 KB

    int gblocks = (N + 63) / 64;     // 64 nodes per block, 4 waves
    int ablocks = (N + 15) / 16;     // 4 waves/block, 4 nodes per wave

    // ---- CSR build + weight prep ----
    zero_ints<<<(NB + 255) / 256, 256, 0, stream>>>(bcur, NB);
    prep_wt<<<32, 256, 0, stream>>>(W0, W1, W2, W3, wt0, wt1, wt2, wt3);
    bucket_kernel<<<(E + CHUNK - 1) / CHUNK, 512, 0, stream>>>(src, tgt, mw, bcur, bkt, brow, E, NB);
    bscan_kernel<<<1, 512, 0, stream>>>(bcur, bbase, row_start, NB, N);
    rowsort_kernel<<<NB, 1024, 0, stream>>>(bkt, brow, bcur, bbase, csr, row_start, N);

    // ---- Layer 0: h = relu(A @ (x @ W0) + b0) ----
    gemm_mfma<128><<<gblocks, 256, 0, stream>>>(x, wt0, (uint*)support, N);
    agg64_kernel<<<ablocks, 256, 0, stream>>>(support, row_start, csr, b0, nullptr, h, N);
    // ---- Layer 1: h = relu(A @ (h @ W1) + b1) + h ----
    gemm_mfma<64><<<gblocks, 256, 0, stream>>>(h, wt1, (uint*)support, N);
    agg64_kernel<<<ablocks, 256, 0, stream>>>(support, row_start, csr, b1, h, h, N);
    // ---- Layer 2 ----
    gemm_mfma<64><<<gblocks, 256, 0, stream>>>(h, wt2, (uint*)support, N);
    agg64_kernel<<<ablocks, 256, 0, stream>>>(support, row_start, csr, b2, h, h, N);
    // ---- Layer 3: out = log_softmax(A @ (h @ W3) + b3); W3 zero-padded ----
    gemm_mfma<64><<<gblocks, 256, 0, stream>>>(h, wt3, (uint*)support, N);
    agg_final_kernel<<<ablocks, 256, 0, stream>>>(support, row_start, csr, b3, out, N);
}

// Round 6
// 334.484 us; speedup vs baseline: 1.1801x; 1.0649x over previous
//
#include <hip/hip_runtime.h>
#include <cstdint>
#include <cstddef>
#include <math.h>

// RESK GCN forward: 4 graph-conv layers + residuals + log_softmax.
// R14: fp8 support table. R13 aggs ~flat vs FETCH pinned at 80MB from a
//      12.8MB bf16 table (205MB gather demand, L2/XCD 4MB << table) ->
//      byte-bound random gather. Support now fp8 e4m3 (64B rows, 6.4MB
//      table ~ L2-sized): MFMA epilogue packs via v_cvt_pk_fp8_f32, agg
//      gathers one dword/lane (4 cols) and decodes via v_cvt_pk_f32_fp8.
//      Weights stay bf16 in MFMA; h stays fp32. 4-nodes-per-wave agg (R13),
//      MFMA GEMM (R11), CSR build unchanged.

typedef unsigned int uint;
typedef unsigned short ushort;
typedef unsigned char uchar;

typedef __attribute__((ext_vector_type(8))) short bf16x8;
typedef __attribute__((ext_vector_type(4))) float f32x4;
typedef __attribute__((ext_vector_type(2))) float f32x2;

constexpr int NB_ROWS = 256;   // rows per bucket
constexpr int CHUNK   = 2048;  // edges per bucket_kernel block
constexpr int CAP     = 4608;  // bucket window capacity (mean 4096, +8 sigma)

__device__ __forceinline__ uint f2bf(float f) {
    uint u = __float_as_uint(f);
    return (u + 0x7FFFu + ((u >> 16) & 1u)) >> 16;
}

__global__ void zero_ints(int* __restrict__ p, int n) {
    int i = blockIdx.x * blockDim.x + threadIdx.x;
    if (i < n) p[i] = 0;
}

// Build bf16 W^T copies: wt0 [64][128]; wt1,wt2 [64][64]; wt3 [64][64]
// (cols >=40 zero). wtX[c][k] = bf16(WX[k][c]).
__global__ void prep_wt(const float* __restrict__ W0, const float* __restrict__ W1,
                        const float* __restrict__ W2, const float* __restrict__ W3,
                        ushort* __restrict__ wt0, ushort* __restrict__ wt1,
                        ushort* __restrict__ wt2, ushort* __restrict__ wt3) {
    int i = blockIdx.x * 256 + threadIdx.x;
    if (i < 64 * 128) {
        int c = i >> 7, k = i & 127;
        wt0[i] = (ushort)f2bf(W0[k * 64 + c]);
    }
    if (i < 64 * 64) {
        int c = i >> 6, k = i & 63;
        wt1[i] = (ushort)f2bf(W1[k * 64 + c]);
        wt2[i] = (ushort)f2bf(W2[k * 64 + c]);
        wt3[i] = (c < 40) ? (ushort)f2bf(W3[k * 40 + c]) : (ushort)0;
    }
}

// Stage 1: bin edges by bucket (tgt>>8) in LDS; write per-(block,bucket) runs
// contiguously. Payload = src | w15<<17 (4B) + row byte (1B side array).
__global__ __launch_bounds__(512) void bucket_kernel(const int* __restrict__ src,
                                                     const int* __restrict__ tgt,
                                                     const float* __restrict__ w,
                                                     int* __restrict__ bcur,
                                                     uint* __restrict__ bkt,
                                                     uchar* __restrict__ brow,
                                                     int E, int NB) {
    __shared__ uint binned[CHUNK];
    __shared__ ushort binb[CHUNK];
    __shared__ uchar binr[CHUNK];
    __shared__ int hist[512];
    __shared__ int sc[512];
    __shared__ int cur[512];
    __shared__ int gbase[512];
    int tid = threadIdx.x;
    int e0 = blockIdx.x * CHUNK;
    int cnt = min(CHUNK, E - e0);
    hist[tid] = 0;
    __syncthreads();
    for (int i = tid; i < cnt; i += 512) atomicAdd(&hist[tgt[e0 + i] >> 8], 1);
    __syncthreads();
    int v = hist[tid];
    sc[tid] = v;
    __syncthreads();
    for (int off = 1; off < 512; off <<= 1) {
        int t = (tid >= off) ? sc[tid - off] : 0;
        __syncthreads();
        sc[tid] += t;
        __syncthreads();
    }
    int excl = sc[tid] - v;
    if (tid < NB && v > 0) gbase[tid] = atomicAdd(&bcur[tid], v);
    __syncthreads();
    hist[tid] = excl;
    cur[tid] = excl;
    __syncthreads();
    for (int i = tid; i < cnt; i += 512) {
        int t = tgt[e0 + i];
        int b = t >> 8;
        int r = atomicAdd(&cur[b], 1);
        float wf = w[e0 + i];
        uint w15 = (uint)(int)(wf * 32767.f + 0.5f);
        if (w15 > 32767u) w15 = 32767u;
        binned[r] = (uint)src[e0 + i] | (w15 << 17);
        binb[r] = (ushort)b;
        binr[r] = (uchar)(t & 255);
    }
    __syncthreads();
    for (int i = tid; i < cnt; i += 512) {
        int b = binb[i];
        int dst = gbase[b] + (i - hist[b]);
        if (dst < CAP) {
            bkt[(size_t)b * CAP + dst] = binned[i];
            brow[(size_t)b * CAP + dst] = binr[i];
        }
    }
}

// Stage 2: exclusive scan of bucket totals -> bucket bases; total -> row_start[N].
__global__ void bscan_kernel(const int* __restrict__ bcur, int* __restrict__ bbase,
                             int* __restrict__ row_start, int NB, int N) {
    __shared__ int sd[512];
    int tid = threadIdx.x;
    int tot = (tid < NB) ? min(bcur[tid], CAP) : 0;
    sd[tid] = tot;
    __syncthreads();
    for (int off = 1; off < 512; off <<= 1) {
        int t = (tid >= off) ? sd[tid - off] : 0;
        __syncthreads();
        sd[tid] += t;
        __syncthreads();
    }
    if (tid < NB) bbase[tid] = sd[tid] - tot;
    if (tid == 511) row_start[N] = sd[511];
}

// Stage 3: per-bucket row sort -> row_start + row-sorted 4B csr entries.
__global__ __launch_bounds__(1024) void rowsort_kernel(const uint* __restrict__ bkt,
                                                       const uchar* __restrict__ brow,
                                                       const int* __restrict__ bcur,
                                                       const int* __restrict__ bbase,
                                                       uint* __restrict__ csr,
                                                       int* __restrict__ row_start, int N) {
    __shared__ int hist[256];
    __shared__ int offs[256];
    int b = blockIdx.x;
    int tid = threadIdx.x;
    int cnt = min(bcur[b], CAP);
    const uint* win = bkt + (size_t)b * CAP;
    const uchar* wrow = brow + (size_t)b * CAP;
    if (tid < 256) hist[tid] = 0;
    __syncthreads();
    uint en[5];
    uchar er[5];
    int ne = 0;
#pragma unroll
    for (int k = 0; k < 5; ++k) {
        int i = tid + k * 1024;
        if (i < cnt) {
            en[k] = win[i];
            er[k] = wrow[i];
            atomicAdd(&hist[er[k]], 1);
            ne = k + 1;
        }
    }
    __syncthreads();
    int v = 0;
    if (tid < 256) { v = hist[tid]; offs[tid] = v; }
    __syncthreads();
    for (int off = 1; off < 256; off <<= 1) {
        int t = 0;
        if (tid < 256 && tid >= off) t = offs[tid - off];
        __syncthreads();
        if (tid < 256) offs[tid] += t;
        __syncthreads();
    }
    int gb = bbase[b];
    if (tid < 256) {
        int excl = offs[tid] - v;
        int row = (b << 8) + tid;
        if (row < N) row_start[row] = gb + excl;
        hist[tid] = excl;
    }
    __syncthreads();
#pragma unroll
    for (int k = 0; k < 5; ++k) {
        if (k < ne) {
            int pos = atomicAdd(&hist[er[k]], 1);
            csr[gb + pos] = en[k];
        }
    }
}

// support[n][c] = sum_k H[n][k] * W[k][c], output fp8 e4m3, row = 64B
// (16 uints). MFMA 16x16x32 bf16, operands swapped: A = Wt (C x K),
// B = H^T (K x nodes) => D[c][node]; lane&15 = node, 4*(lane>>4)+j = c =>
// per lane one node x 4 consecutive cols -> one packed fp8 dword store per
// 16-col tile. Block = 64 nodes x 4 waves. H tile staged fp32->bf16 in LDS,
// byte-col XOR ((row&7)<<4) swizzle, read as bf16x8 (ds_read_b128).
template <int K>
__global__ __launch_bounds__(256) void gemm_mfma(const float* __restrict__ H,
                                                 const ushort* __restrict__ Wt,
                                                 uint* __restrict__ out, int n) {
    constexpr int NT = K / 32;  // K-steps
    __shared__ ushort alds[64 * K];
    int tid = threadIdx.x;
    int nbase = blockIdx.x * 64;
    int rows = min(64, n - nbase);

    // Stage H tile (64 x K fp32) -> bf16 LDS, coalesced float4 reads.
    const float4* Hg = (const float4*)(H + (size_t)nbase * K);
#pragma unroll
    for (int it = 0; it < K / 16; ++it) {
        int i = tid + it * 256;     // float4 index within tile
        int r = i / (K / 4);
        int c4 = i % (K / 4);
        if (r < rows) {
            float4 v = Hg[i];
            uint2 pk;
            pk.x = f2bf(v.x) | (f2bf(v.y) << 16);
            pk.y = f2bf(v.z) | (f2bf(v.w) << 16);
            uint bcol = ((uint)(c4 * 8)) ^ (((uint)(r & 7)) << 4);
            *(uint2*)((char*)alds + r * (K * 2) + bcol) = pk;
        }
    }

    int wv = __builtin_amdgcn_readfirstlane(tid >> 6);
    int l = tid & 63;
    int lr = l & 15;
    int lh = l >> 4;

    // A-operand fragments: Wt[c = ct*16+lr][k = ks*32 + lh*8 .. +8].
    bf16x8 wf[4][NT];
#pragma unroll
    for (int ct = 0; ct < 4; ++ct)
#pragma unroll
        for (int ks = 0; ks < NT; ++ks)
            wf[ct][ks] = *(const bf16x8*)(const void*)(Wt + (ct * 16 + lr) * K + ks * 32 + lh * 8);

    __syncthreads();

    f32x4 acc[4];
#pragma unroll
    for (int ct = 0; ct < 4; ++ct) acc[ct] = (f32x4){0.f, 0.f, 0.f, 0.f};

    int row = wv * 16 + lr;  // node within tile
#pragma unroll
    for (int ks = 0; ks < NT; ++ks) {
        uint bcol = ((uint)(ks * 64 + lh * 16)) ^ (((uint)(row & 7)) << 4);
        bf16x8 hf = *(const bf16x8*)((const char*)alds + row * (K * 2) + bcol);
#pragma unroll
        for (int ct = 0; ct < 4; ++ct)
            acc[ct] = __builtin_amdgcn_mfma_f32_16x16x32_bf16(wf[ct][ks], hf, acc[ct], 0, 0, 0);
    }

    int node = nbase + row;
    if (node < n) {
        uint* orow = out + (size_t)node * 16;  // 64 fp8 = 16 uints per row
#pragma unroll
        for (int ct = 0; ct < 4; ++ct) {
            uint p = 0;
            p = __builtin_amdgcn_cvt_pk_fp8_f32(acc[ct][0], acc[ct][1], p, false);
            p = __builtin_amdgcn_cvt_pk_fp8_f32(acc[ct][2], acc[ct][3], p, true);
            orow[ct * 4 + lh] = p;  // cols ct*16 + lh*4 .. +3
        }
    }
}

__device__ __forceinline__ float wval(uint d) {
    return (float)(d >> 17) * (1.0f / 32767.f);
}

// 4-nodes-per-wave agg body over fp8 support (64B rows). Lane group
// g=lane>>4 owns node n0+g; c=lane&15 owns cols 4c..4c+3 (one dword gather,
// 16 lanes cover the 64B row; decode via v_cvt_pk_f32_fp8). The 4 nodes'
// csr ranges are contiguous (row-sorted csr): coop-load 64-entry windows;
// group g consumes its slice in rounds of 4 edges (bpermute broadcast;
// dead lanes masked to entry 0 -> w=0). Full per-node sums (no combine).
__device__ __forceinline__ void agg4_body(const uchar* __restrict__ sb,
                                          const int* __restrict__ row_start,
                                          const uint* __restrict__ csr, int n0,
                                          int lane, int N, float& a0, float& a1,
                                          float& a2, float& a3) {
    int g = lane >> 4;
    uint voff = (uint)((lane & 15) << 2);

    int idx = n0 + lane;
    if (idx > N) idx = N;
    int rsv = (lane <= 4) ? row_start[idx] : 0;
    int rs0 = __shfl(rsv, 0);
    int myb = __shfl(rsv, g);       // this node's range begin
    int mye = __shfl(rsv, g + 1);   // this node's range end
    int tend = __shfl(rsv, 4);      // end of wave's 4-node span

    for (int W0 = rs0; W0 < tend; W0 += 64) {
        int ei = W0 + lane;
        uint entry = (ei < tend) ? csr[ei] : 0u;
        int lo = myb - W0;
        if (lo < 0) lo = 0;
        int hi = mye - W0;
        if (hi > 64) hi = 64;
        int cnt = hi - lo;
        if (cnt < 0) cnt = 0;
        // wave-uniform max rounds (keep all lanes active through bpermute)
        int mx = cnt;
        mx = max(mx, __shfl_xor(mx, 16));
        mx = max(mx, __shfl_xor(mx, 32));
        for (int o = 0; o < mx; o += 4) {
            uint dd[4];
            uint uu[4];
#pragma unroll
            for (int j = 0; j < 4; ++j) {
                int p = (lo + o + j) & 63;
                uint d = (uint)__builtin_amdgcn_ds_bpermute(p << 2, (int)entry);
                dd[j] = ((o + j) < cnt) ? d : 0u;
            }
#pragma unroll
            for (int j = 0; j < 4; ++j)
                uu[j] = *(const uint*)(sb + (((dd[j] & 0x1FFFFu) << 6) | voff));
#pragma unroll
            for (int j = 0; j < 4; ++j) {
                float wv = wval(dd[j]);
                f32x2 flo = __builtin_amdgcn_cvt_pk_f32_fp8(uu[j], false);
                f32x2 fhi = __builtin_amdgcn_cvt_pk_f32_fp8(uu[j], true);
                a0 = fmaf(flo[0], wv, a0);
                a1 = fmaf(flo[1], wv, a1);
                a2 = fmaf(fhi[0], wv, a2);
                a3 = fmaf(fhi[1], wv, a3);
            }
        }
    }
}

// Middle layers: relu(agg + bias) (+ resid). All 64 lanes write: group g
// stores node n0+g cols 4c..4c+3. out may alias resid.
__global__ __launch_bounds__(256) void agg64_kernel(const uchar* __restrict__ sb,
                                                    const int* __restrict__ row_start,
                                                    const uint* __restrict__ csr,
                                                    const float* __restrict__ bias,
                                                    const float* __restrict__ resid,
                                                    float* __restrict__ out, int n) {
    int wid = (blockIdx.x * blockDim.x + threadIdx.x) >> 6;   // wave id
    int lane = threadIdx.x & 63;
    int n0 = wid * 4;
    if (n0 >= n) return;
    float a0 = 0.f, a1 = 0.f, a2 = 0.f, a3 = 0.f;
    agg4_body(sb, row_start, csr, n0, lane, n, a0, a1, a2, a3);
    int g = lane >> 4;
    int c = lane & 15;
    int nd = n0 + g;
    if (nd < n) {
        float4 bv = *(const float4*)(bias + 4 * c);
        float h0 = fmaxf(a0 + bv.x, 0.f);
        float h1 = fmaxf(a1 + bv.y, 0.f);
        float h2 = fmaxf(a2 + bv.z, 0.f);
        float h3 = fmaxf(a3 + bv.w, 0.f);
        if (resid) {
            float4 rv = *(const float4*)(resid + (size_t)nd * 64 + 4 * c);
            h0 += rv.x;
            h1 += rv.y;
            h2 += rv.z;
            h3 += rv.w;
        }
        *(float4*)(out + (size_t)nd * 64 + 4 * c) = make_float4(h0, h1, h2, h3);
    }
}

// Final layer: agg over fp8 support (cols 0..39 live) + bias + fused
// log_softmax; reductions run within each 16-lane group (xor 1,2,4,8), so
// the wave's 4 nodes compute softmax in parallel.
__global__ __launch_bounds__(256) void agg_final_kernel(const uchar* __restrict__ sb,
                                                        const int* __restrict__ row_start,
                                                        const uint* __restrict__ csr,
                                                        const float* __restrict__ bias,
                                                        float* __restrict__ out, int n) {
    int wid = (blockIdx.x * blockDim.x + threadIdx.x) >> 6;
    int lane = threadIdx.x & 63;
    int n0 = wid * 4;
    if (n0 >= n) return;
    float a0 = 0.f, a1 = 0.f, a2 = 0.f, a3 = 0.f;
    agg4_body(sb, row_start, csr, n0, lane, n, a0, a1, a2, a3);
    int g = lane >> 4;
    int c = lane & 15;
    int nd = n0 + g;
    bool act = c < 10;  // cols 4c..4c+3 < 40
    float v0 = -INFINITY, v1 = -INFINITY, v2 = -INFINITY, v3 = -INFINITY;
    if (act) {
        float4 bv = *(const float4*)(bias + 4 * c);
        v0 = a0 + bv.x;
        v1 = a1 + bv.y;
        v2 = a2 + bv.z;
        v3 = a3 + bv.w;
    }
    float m = fmaxf(fmaxf(v0, v1), fmaxf(v2, v3));
#pragma unroll
    for (int d = 1; d < 16; d <<= 1) m = fmaxf(m, __shfl_xor(m, d));
    float ex = act ? (expf(v0 - m) + expf(v1 - m) + expf(v2 - m) + expf(v3 - m)) : 0.f;
#pragma unroll
    for (int d = 1; d < 16; d <<= 1) ex += __shfl_xor(ex, d);
    float lse = m + logf(ex);
    if (act && nd < n)
        *(float4*)(out + (size_t)nd * 40 + 4 * c) =
            make_float4(v0 - lse, v1 - lse, v2 - lse, v3 - lse);
}

extern "C" void kernel_launch(void* const* d_in, const int* in_sizes, int n_in,
                              void* d_out, int out_size, void* d_ws, size_t ws_size,
                              hipStream_t stream) {
    const float* x   = (const float*)d_in[0];
    const int*   src = (const int*)d_in[1];
    const int*   tgt = (const int*)d_in[2];
    const float* mw  = (const float*)d_in[3];
    const float* W0  = (const float*)d_in[4];
    const float* b0  = (const float*)d_in[5];
    const float* W1  = (const float*)d_in[6];
    const float* b1  = (const float*)d_in[7];
    const float* W2  = (const float*)d_in[8];
    const float* b2  = (const float*)d_in[9];
    const float* W3  = (const float*)d_in[10];
    const float* b3  = (const float*)d_in[11];
    float* out = (float*)d_out;

    const int N = in_sizes[0] / 128;
    const int E = in_sizes[1];
    const int NB = (N + NB_ROWS - 1) / NB_ROWS;  // 391 buckets (<=512)

    // Workspace carve-out (~50 MB)
    char* p = (char*)d_ws;
    auto carve = [&](size_t bytes) {
        char* r = p;
        p += (bytes + 255) & ~size_t(255);
        return r;
    };
    int*    bcur      = (int*)carve((size_t)NB * 4);
    int*    bbase     = (int*)carve((size_t)NB * 4);
    int*    row_start = (int*)carve((size_t)(N + 1) * 4);
    uint*   bkt       = (uint*)carve((size_t)NB * CAP * 4);   // 7.2 MB
    uchar*  brow      = (uchar*)carve((size_t)NB * CAP);      // 1.8 MB
    uint*   csr       = (uint*)carve((size_t)E * 4);          // 6.4 MB
    uchar*  support   = (uchar*)carve((size_t)N * 64);        // 6.4 MB (fp8, 64B rows)
    float*  h         = (float*)carve((size_t)N * 64 * 4);    // 25.6 MB
    ushort* wt0       = (ushort*)carve((size_t)64 * 128 * 2); // 16 KB
    ushort* wt1       = (ushort*)carve((size_t)64 * 64 * 2);  // 8 KB
    ushort* wt2       = (ushort*)carve((size_t)64 * 64 * 2);  // 8 KB
    ushort* wt3       = (ushort*)carve((size_t)64 * 64 * 2);  // 8 KB

    int gblocks = (N + 63) / 64;     // 64 nodes per block, 4 waves
    int ablocks = (N + 15) / 16;     // 4 waves/block, 4 nodes per wave

    // ---- CSR build + weight prep ----
    zero_ints<<<(NB + 255) / 256, 256, 0, stream>>>(bcur, NB);
    prep_wt<<<32, 256, 0, stream>>>(W0, W1, W2, W3, wt0, wt1, wt2, wt3);
    bucket_kernel<<<(E + CHUNK - 1) / CHUNK, 512, 0, stream>>>(src, tgt, mw, bcur, bkt, brow, E, NB);
    bscan_kernel<<<1, 512, 0, stream>>>(bcur, bbase, row_start, NB, N);
    rowsort_kernel<<<NB, 1024, 0, stream>>>(bkt, brow, bcur, bbase, csr, row_start, N);

    // ---- Layer 0: h = relu(A @ (x @ W0) + b0) ----
    gemm_mfma<128><<<gblocks, 256, 0, stream>>>(x, wt0, (uint*)support, N);
    agg64_kernel<<<ablocks, 256, 0, stream>>>(support, row_start, csr, b0, nullptr, h, N);
    // ---- Layer 1: h = relu(A @ (h @ W1) + b1) + h ----
    gemm_mfma<64><<<gblocks, 256, 0, stream>>>(h, wt1, (uint*)support, N);
    agg64_kernel<<<ablocks, 256, 0, stream>>>(support, row_start, csr, b1, h, h, N);
    // ---- Layer 2 ----
    gemm_mfma<64><<<gblocks, 256, 0, stream>>>(h, wt2, (uint*)support, N);
    agg64_kernel<<<ablocks, 256, 0, stream>>>(support, row_start, csr, b2, h, h, N);
    // ---- Layer 3: out = log_softmax(A @ (h @ W3) + b3); W3 zero-padded ----
    gemm_mfma<64><<<gblocks, 256, 0, stream>>>(h, wt3, (uint*)support, N);
    agg_final_kernel<<<ablocks, 256, 0, stream>>>(support, row_start, csr, b3, out, N);
}